// Round 4
// baseline (1066.040 us; speedup 1.0000x reference)
//
#include <hip/hip_runtime.h>
#include <hip/hip_bf16.h>
#include <stdint.h>

// ---------------------------------------------------------------------------
// GCN encoder: binned scatter-add (segment_sum) -> relu -> GEMM1(978->2048)
// + relu -> GEMM2(2048->100). bf16 MFMA for both GEMMs (fp32 accumulate).
//
// R4: binscatter write-amplification fix (1024 WGs -> 80B runs/line),
// NT loads on streaming edges to protect the 16MB gather table's L2 slice,
// transposed hist layout (all coalesced), accum+act fusion, gemm2 KSPLIT 2.
// ---------------------------------------------------------------------------

typedef unsigned short u16;
typedef unsigned int u32;
typedef unsigned long long u64;
typedef __bf16 bf16x8 __attribute__((ext_vector_type(8)));
typedef float f32x4 __attribute__((ext_vector_type(4)));

#define NGENES 978
#define KPAD   1024
#define H1DIM  2048
#define NOUT   100
#define NOUTP  112   // padded to 7 * 16
#define KSPLIT 2

// scatter binning: 8,011,776 nodes = 978 buckets x 8192 nodes (exact)
#define NB      978
#define BSH     13
#define BNODES  8192
#define NWG_BIN 1024
#define BTHR    512
#define HSTRIDE 1024   // hist row stride (u32), layout hist[wg*HSTRIDE + b]

// round-to-nearest-even f32 -> bf16
__device__ __forceinline__ u16 f2b(float f) {
    unsigned u = __builtin_bit_cast(unsigned, f);
    u = (u + 0x7FFFu + ((u >> 16) & 1u)) >> 16;
    return (u16)u;
}

// async 16B global -> LDS direct copy (wave-uniform base + lane*16 layout)
__device__ __forceinline__ void gl2lds16(const void* g, void* l) {
    __builtin_amdgcn_global_load_lds(
        (const __attribute__((address_space(1))) void*)(uintptr_t)g,
        (__attribute__((address_space(3))) void*)(unsigned)(uintptr_t)l,
        16, 0, 0);
}

// ---------------------------------------------------------------------------
// Detect whether edges buffer is int64 (odd 4-byte words all zero) or int32.
// ---------------------------------------------------------------------------
__global__ void detect_kernel(const unsigned* __restrict__ e, int* __restrict__ flag) {
    if (threadIdx.x == 0) {
        int is64 = 1;
        for (int i = 0; i < 64; ++i) {
            if (e[2 * i + 1] != 0u) { is64 = 0; break; }
        }
        *flag = is64;
    }
}

// ---------------------------------------------------------------------------
// xb[n] = bf16(inputs[n] * gcn_w) — the gather table (16 MB).
// ---------------------------------------------------------------------------
__global__ void xbf_kernel(const float* __restrict__ x, const float* __restrict__ gcn_w,
                           u16* __restrict__ xb, int N) {
    const float w = gcn_w[0];
    int i = (blockIdx.x * 256 + threadIdx.x) * 4;
    if (i + 3 < N) {
        float4 v = *(const float4*)&x[i];
        xb[i + 0] = f2b(v.x * w);
        xb[i + 1] = f2b(v.y * w);
        xb[i + 2] = f2b(v.z * w);
        xb[i + 3] = f2b(v.w * w);
    } else {
        for (int k = i; k < N; ++k) xb[k] = f2b(x[k] * w);
    }
}

// ---------------------------------------------------------------------------
// Kernel A: per-chunk bucket histogram of dst. 8-deep batched, NT edge loads.
// hist layout row-major per WG: hist[wg * HSTRIDE + b]  (coalesced writes).
// ---------------------------------------------------------------------------
__global__ __launch_bounds__(BTHR) void hist_kernel(const void* __restrict__ edges,
                                                    const int* __restrict__ flag, int E,
                                                    u32* __restrict__ hist) {
    __shared__ u32 h[NB];
    for (int i = threadIdx.x; i < NB; i += BTHR) h[i] = 0;
    __syncthreads();
    const int wg = blockIdx.x;
    const int per = (E + NWG_BIN - 1) / NWG_BIN;
    const int s = wg * per;
    const int e = min(E, s + per);
    int i = s + threadIdx.x;
    if (*flag) {
        const u64* dst64 = (const u64*)edges + E;
        for (; i + 7 * BTHR < e; i += 8 * BTHR) {
            u32 d[8];
#pragma unroll
            for (int k = 0; k < 8; ++k) d[k] = (u32)__builtin_nontemporal_load(dst64 + i + k * BTHR);
#pragma unroll
            for (int k = 0; k < 8; ++k) atomicAdd(&h[d[k] >> BSH], 1u);
        }
        for (; i < e; i += BTHR) atomicAdd(&h[(u32)__builtin_nontemporal_load(dst64 + i) >> BSH], 1u);
    } else {
        const u32* dst32 = (const u32*)edges + E;
        for (; i + 7 * BTHR < e; i += 8 * BTHR) {
            u32 d[8];
#pragma unroll
            for (int k = 0; k < 8; ++k) d[k] = __builtin_nontemporal_load(dst32 + i + k * BTHR);
#pragma unroll
            for (int k = 0; k < 8; ++k) atomicAdd(&h[d[k] >> BSH], 1u);
        }
        for (; i < e; i += BTHR) atomicAdd(&h[__builtin_nontemporal_load(dst32 + i) >> BSH], 1u);
    }
    __syncthreads();
    for (int b = threadIdx.x; b < NB; b += BTHR) hist[(size_t)wg * HSTRIDE + b] = h[b];
}

// ---------------------------------------------------------------------------
// Kernel B: column-wise exclusive scan of hist over wg (coalesced: thread t
// owns bucket blockIdx*256+t, walks 1024 rows). In-place; totals out.
// ---------------------------------------------------------------------------
__global__ __launch_bounds__(256) void scan_col_kernel(u32* __restrict__ hist,
                                                       u32* __restrict__ totals) {
    const int b = blockIdx.x * 256 + threadIdx.x;
    const bool act = b < NB;
    u32 running = 0;
    for (int wg = 0; wg < NWG_BIN; wg += 4) {
        size_t i0 = (size_t)wg * HSTRIDE + b;
        u32 v0 = act ? hist[i0] : 0;
        u32 v1 = act ? hist[i0 + HSTRIDE] : 0;
        u32 v2 = act ? hist[i0 + 2 * HSTRIDE] : 0;
        u32 v3 = act ? hist[i0 + 3 * HSTRIDE] : 0;
        if (act) {
            hist[i0] = running;
            hist[i0 + HSTRIDE] = running + v0;
            hist[i0 + 2 * HSTRIDE] = running + v0 + v1;
            hist[i0 + 3 * HSTRIDE] = running + v0 + v1 + v2;
        }
        running += v0 + v1 + v2 + v3;
    }
    if (act) totals[b] = running;
}

// ---------------------------------------------------------------------------
// Kernel B2: exclusive scan of NB bucket totals -> bases[0..NB] (bases[NB]=E).
// ---------------------------------------------------------------------------
__global__ void scan_bucket_kernel(const u32* __restrict__ totals, u32* __restrict__ bases) {
    const int lane = threadIdx.x;
    u32 running = 0;
    const int iters = (NB + 63) / 64;
    for (int it = 0; it < iters; ++it) {
        int idx = it * 64 + lane;
        u32 v = (idx < NB) ? totals[idx] : 0;
        u32 incl = v;
#pragma unroll
        for (int off = 1; off < 64; off <<= 1) {
            u32 t = __shfl_up(incl, off, 64);
            if (lane >= off) incl += t;
        }
        if (idx < NB) bases[idx] = running + incl - v;
        running += __shfl(incl, 63, 64);
    }
    if (lane == 0) bases[NB] = running;
}

// ---------------------------------------------------------------------------
// Kernel C: scatter edges into bucket-grouped packed pairs. 8-deep batched,
// NT edge loads (protect xb's L2 residency), cached xb gather.
// pair = (dst_local << 16) | xb[src].
// ---------------------------------------------------------------------------
__global__ __launch_bounds__(BTHR) void binscatter_kernel(const void* __restrict__ edges,
                                                          const u16* __restrict__ xb,
                                                          const int* __restrict__ flag, int E,
                                                          const u32* __restrict__ hist,
                                                          const u32* __restrict__ bases,
                                                          u32* __restrict__ pairs) {
    __shared__ u32 cur[NB];
    const int wg = blockIdx.x;
    for (int b = threadIdx.x; b < NB; b += BTHR)
        cur[b] = bases[b] + hist[(size_t)wg * HSTRIDE + b];
    __syncthreads();
    const int per = (E + NWG_BIN - 1) / NWG_BIN;
    const int s = wg * per;
    const int e = min(E, s + per);
    int i = s + threadIdx.x;
    if (*flag) {
        const u64* es = (const u64*)edges;
        const u64* ed = es + E;
        for (; i + 7 * BTHR < e; i += 8 * BTHR) {
            u32 src[8], d[8];
            u16 val[8];
#pragma unroll
            for (int k = 0; k < 8; ++k) src[k] = (u32)__builtin_nontemporal_load(es + i + k * BTHR);
#pragma unroll
            for (int k = 0; k < 8; ++k) d[k] = (u32)__builtin_nontemporal_load(ed + i + k * BTHR);
#pragma unroll
            for (int k = 0; k < 8; ++k) val[k] = xb[src[k]];
#pragma unroll
            for (int k = 0; k < 8; ++k) {
                u32 pos = atomicAdd(&cur[d[k] >> BSH], 1u);
                pairs[pos] = ((d[k] & (BNODES - 1)) << 16) | (u32)val[k];
            }
        }
        for (; i < e; i += BTHR) {
            u32 src = (u32)__builtin_nontemporal_load(es + i);
            u32 d = (u32)__builtin_nontemporal_load(ed + i);
            u16 v = xb[src];
            u32 pos = atomicAdd(&cur[d >> BSH], 1u);
            pairs[pos] = ((d & (BNODES - 1)) << 16) | (u32)v;
        }
    } else {
        const u32* es = (const u32*)edges;
        const u32* ed = es + E;
        for (; i + 7 * BTHR < e; i += 8 * BTHR) {
            u32 src[8], d[8];
            u16 val[8];
#pragma unroll
            for (int k = 0; k < 8; ++k) src[k] = __builtin_nontemporal_load(es + i + k * BTHR);
#pragma unroll
            for (int k = 0; k < 8; ++k) d[k] = __builtin_nontemporal_load(ed + i + k * BTHR);
#pragma unroll
            for (int k = 0; k < 8; ++k) val[k] = xb[src[k]];
#pragma unroll
            for (int k = 0; k < 8; ++k) {
                u32 pos = atomicAdd(&cur[d[k] >> BSH], 1u);
                pairs[pos] = ((d[k] & (BNODES - 1)) << 16) | (u32)val[k];
            }
        }
        for (; i < e; i += BTHR) {
            u32 src = __builtin_nontemporal_load(es + i);
            u32 d = __builtin_nontemporal_load(ed + i);
            u16 v = xb[src];
            u32 pos = atomicAdd(&cur[d >> BSH], 1u);
            pairs[pos] = ((d & (BNODES - 1)) << 16) | (u32)v;
        }
    }
}

// ---------------------------------------------------------------------------
// Kernel D: per-bucket LDS accumulate (32KB fp32 tile) + FUSED epilogue:
// bias + relu + bf16 + KPAD remap, writes A directly (act_kernel removed).
// ---------------------------------------------------------------------------
__global__ __launch_bounds__(512) void accum_kernel(const u32* __restrict__ pairs,
                                                    const u32* __restrict__ bases,
                                                    const float* __restrict__ gcn_b,
                                                    u16* __restrict__ A) {
    __shared__ float acc[BNODES];    // 32 KB
    for (int i = threadIdx.x; i < BNODES; i += 512) acc[i] = 0.f;
    __syncthreads();
    const int b = blockIdx.x;
    const u32 p0 = bases[b], p1 = bases[b + 1];
    u32 p = p0 + threadIdx.x;
    for (; p + 3 * 512 < p1; p += 4 * 512) {
        u32 pk[4];
#pragma unroll
        for (int k = 0; k < 4; ++k) pk[k] = __builtin_nontemporal_load(pairs + p + k * 512);
#pragma unroll
        for (int k = 0; k < 4; ++k) {
            float v = __builtin_bit_cast(float, (pk[k] & 0xFFFFu) << 16);
            atomicAdd(&acc[pk[k] >> 16], v);
        }
    }
    for (; p < p1; p += 512) {
        u32 pk = __builtin_nontemporal_load(pairs + p);
        float v = __builtin_bit_cast(float, (pk & 0xFFFFu) << 16);
        atomicAdd(&acc[pk >> 16], v);
    }
    __syncthreads();
    const float bias = gcn_b[0];
    const u32 node0 = (u32)b << BSH;
    for (int i = threadIdx.x; i < BNODES; i += 512) {
        u32 n = node0 + i;
        u32 row = n / NGENES;                 // compiler magic-div
        u32 gene = n - row * NGENES;
        float v = acc[i] + bias;
        v = v > 0.f ? v : 0.f;
        A[(size_t)row * KPAD + gene] = f2b(v);
    }
}

// ---------------------------------------------------------------------------
// Zero the K-pad columns A[:, 978:1024].
// ---------------------------------------------------------------------------
__global__ void pad_kernel(u16* __restrict__ A, int Brows) {
    int idx = blockIdx.x * 256 + threadIdx.x;
    int row = idx / (KPAD - NGENES);
    int k = idx - row * (KPAD - NGENES);
    if (row < Brows) A[(size_t)row * KPAD + NGENES + k] = 0;
}

// ---------------------------------------------------------------------------
// Legacy fallback path (workspace too small): direct atomics + act.
// ---------------------------------------------------------------------------
__global__ void scatter_kernel(const void* __restrict__ edges, const float* __restrict__ x,
                               const float* __restrict__ gcn_w, float* __restrict__ agg,
                               const int* __restrict__ flag, int E) {
    long long e = (long long)blockIdx.x * 256 + threadIdx.x;
    if (e >= E) return;
    int s, d;
    if (*flag) {
        const long long* e64 = (const long long*)edges;
        s = (int)e64[e];
        d = (int)e64[(long long)E + e];
    } else {
        const int* e32 = (const int*)edges;
        s = e32[e];
        d = e32[(long long)E + e];
    }
    atomicAdd(&agg[d], x[s] * gcn_w[0]);
}

__global__ void act_kernel(const float* __restrict__ agg, const float* __restrict__ gcn_b,
                           u16* __restrict__ A) {
    int idx = blockIdx.x * 256 + threadIdx.x;
    int i = idx >> 10;
    int k = idx & 1023;
    float v = 0.f;
    if (k < NGENES) {
        v = agg[(size_t)i * NGENES + k] + gcn_b[0];
        v = v > 0.f ? v : 0.f;
    }
    A[idx] = f2b(v);
}

// ---------------------------------------------------------------------------
// W1 [978][2048] f32 -> W1T [2048][1024] bf16 (transposed, K zero-padded)
// ---------------------------------------------------------------------------
__global__ void transposeW1(const float* __restrict__ W1, u16* __restrict__ W1T) {
    __shared__ float t[32][33];
    int n0 = blockIdx.x * 32;
    int k0 = blockIdx.y * 32;
    int tx = threadIdx.x, ty = threadIdx.y;
    for (int r = ty; r < 32; r += 8) {
        int k = k0 + r;
        t[r][tx] = (k < NGENES) ? W1[(size_t)k * H1DIM + n0 + tx] : 0.f;
    }
    __syncthreads();
    for (int r = ty; r < 32; r += 8) {
        int n = n0 + r;
        W1T[(size_t)n * KPAD + k0 + tx] = f2b(t[tx][r]);
    }
}

// ---------------------------------------------------------------------------
// W2 [2048][100] f32 -> W2T [112][2048] bf16 (transposed, N zero-padded)
// ---------------------------------------------------------------------------
__global__ void transposeW2(const float* __restrict__ W2, u16* __restrict__ W2T) {
    __shared__ float t[32][33];
    int n0 = blockIdx.x * 32;
    int k0 = blockIdx.y * 32;
    int tx = threadIdx.x, ty = threadIdx.y;
    for (int r = ty; r < 32; r += 8) {
        int k = k0 + r;
        int n = n0 + tx;
        t[r][tx] = (n < NOUT) ? W2[(size_t)k * NOUT + n] : 0.f;
    }
    __syncthreads();
    for (int r = ty; r < 32; r += 8) {
        int n = n0 + r;
        if (n < NOUTP) W2T[(size_t)n * H1DIM + k0 + tx] = f2b(t[tx][r]);
    }
}

// ---------------------------------------------------------------------------
// GEMM1: H[8192][2048] = relu(A[8192][1024] @ W1T^T + b1), bf16 out.
// 128x128 tile, BK=32, 4 waves 2x2, 16x16x32 MFMA, global_load_lds width=16.
// ---------------------------------------------------------------------------
__global__ __launch_bounds__(256) void gemm1_kernel(const u16* __restrict__ A,
                                                    const u16* __restrict__ Bt,
                                                    const float* __restrict__ b1,
                                                    u16* __restrict__ H) {
    __shared__ u16 As[128 * 32];
    __shared__ u16 Bs[128 * 32];
    const int tid = threadIdx.x;
    const int m0 = blockIdx.y * 128;
    const int n0 = blockIdx.x * 128;
    const int wave = tid >> 6;
    const int lane = tid & 63;
    const int wm = (wave >> 1) * 64;
    const int wn = (wave & 1) * 64;
    const int quad = lane >> 4;
    const int l16 = lane & 15;

    f32x4 acc[4][4];
#pragma unroll
    for (int i = 0; i < 4; ++i)
#pragma unroll
        for (int j = 0; j < 4; ++j)
            acc[i][j] = (f32x4){0.f, 0.f, 0.f, 0.f};

    const int ch0 = tid, ch1 = tid + 256;
    const u16* ag0 = A + (size_t)(m0 + (ch0 >> 2)) * KPAD + (ch0 & 3) * 8;
    const u16* ag1 = A + (size_t)(m0 + (ch1 >> 2)) * KPAD + (ch1 & 3) * 8;
    const u16* bg0 = Bt + (size_t)(n0 + (ch0 >> 2)) * KPAD + (ch0 & 3) * 8;
    const u16* bg1 = Bt + (size_t)(n0 + (ch1 >> 2)) * KPAD + (ch1 & 3) * 8;
    u16* la0 = &As[ch0 * 8];
    u16* la1 = &As[ch1 * 8];
    u16* lb0 = &Bs[ch0 * 8];
    u16* lb1 = &Bs[ch1 * 8];

    for (int k0 = 0; k0 < KPAD; k0 += 32) {
        gl2lds16(ag0, la0);
        gl2lds16(ag1, la1);
        gl2lds16(bg0, lb0);
        gl2lds16(bg1, lb1);
        ag0 += 32; ag1 += 32; bg0 += 32; bg1 += 32;
        __syncthreads();

        bf16x8 af[4], bfr[4];
#pragma unroll
        for (int i = 0; i < 4; ++i)
            af[i] = *(const bf16x8*)&As[(wm + i * 16 + l16) * 32 + quad * 8];
#pragma unroll
        for (int j = 0; j < 4; ++j)
            bfr[j] = *(const bf16x8*)&Bs[(wn + j * 16 + l16) * 32 + quad * 8];
#pragma unroll
        for (int i = 0; i < 4; ++i)
#pragma unroll
            for (int j = 0; j < 4; ++j)
                acc[i][j] = __builtin_amdgcn_mfma_f32_16x16x32_bf16(af[i], bfr[j], acc[i][j], 0, 0, 0);
        __syncthreads();
    }

#pragma unroll
    for (int j = 0; j < 4; ++j) {
        const int col = n0 + wn + j * 16 + l16;
        const float bv = b1[col];
#pragma unroll
        for (int i = 0; i < 4; ++i) {
            const int rbase = m0 + wm + i * 16 + quad * 4;
#pragma unroll
            for (int r = 0; r < 4; ++r) {
                float v = acc[i][j][r] + bv;
                v = v > 0.f ? v : 0.f;
                H[(size_t)(rbase + r) * H1DIM + col] = f2b(v);
            }
        }
    }
}

// ---------------------------------------------------------------------------
// GEMM2: out[8192][100] += H[8192][2048] @ W2T^T + b2, split-K=2 with atomics.
// ---------------------------------------------------------------------------
__global__ __launch_bounds__(256) void gemm2_kernel(const u16* __restrict__ Hh,
                                                    const u16* __restrict__ W2T,
                                                    const float* __restrict__ b2,
                                                    float* __restrict__ out) {
    __shared__ u16 As[64 * 32];
    __shared__ u16 Bs[NOUTP * 32];
    const int tid = threadIdx.x;
    const int m0 = blockIdx.y * 64;
    const int kc = blockIdx.x;
    const int kbase = kc * (H1DIM / KSPLIT);
    const int wave = tid >> 6;
    const int lane = tid & 63;
    const int quad = lane >> 4;
    const int l16 = lane & 15;

    f32x4 acc[7];
#pragma unroll
    for (int j = 0; j < 7; ++j) acc[j] = (f32x4){0.f, 0.f, 0.f, 0.f};

    const u16* ag = Hh + (size_t)(m0 + (tid >> 2)) * H1DIM + kbase + (tid & 3) * 8;
    u16* la = &As[tid * 8];
    const u16* bg0 = W2T + (size_t)(tid >> 2) * H1DIM + kbase + (tid & 3) * 8;
    u16* lb0 = &Bs[tid * 8];
    const int ch1 = tid + 256;
    const u16* bg1 = W2T + (size_t)(ch1 >> 2) * H1DIM + kbase + (ch1 & 3) * 8;
    u16* lb1 = &Bs[ch1 * 8];
    const bool bact = (ch1 < NOUTP * 4);

    for (int kk = 0; kk < H1DIM / KSPLIT; kk += 32) {
        gl2lds16(ag, la);
        gl2lds16(bg0, lb0);
        if (bact) gl2lds16(bg1, lb1);
        ag += 32; bg0 += 32; bg1 += 32;
        __syncthreads();

        bf16x8 af = *(const bf16x8*)&As[(wave * 16 + l16) * 32 + quad * 8];
#pragma unroll
        for (int j = 0; j < 7; ++j) {
            bf16x8 bfr = *(const bf16x8*)&Bs[(j * 16 + l16) * 32 + quad * 8];
            acc[j] = __builtin_amdgcn_mfma_f32_16x16x32_bf16(af, bfr, acc[j], 0, 0, 0);
        }
        __syncthreads();
    }

#pragma unroll
    for (int j = 0; j < 7; ++j) {
        const int col = j * 16 + l16;
        if (col < NOUT) {
            const float bv = (kc == 0) ? b2[col] : 0.f;
            const int rbase = m0 + wave * 16 + quad * 4;
#pragma unroll
            for (int r = 0; r < 4; ++r)
                atomicAdd(&out[(size_t)(rbase + r) * NOUT + col], acc[j][r] + bv);
        }
    }
}

// ---------------------------------------------------------------------------
extern "C" void kernel_launch(void* const* d_in, const int* in_sizes, int n_in,
                              void* d_out, int out_size, void* d_ws, size_t ws_size,
                              hipStream_t stream) {
    const float* inputs = (const float*)d_in[0];
    const void*  edges  = d_in[1];
    const float* gcn_w  = (const float*)d_in[2];
    const float* gcn_b  = (const float*)d_in[3];
    const float* W1     = (const float*)d_in[4];
    const float* b1     = (const float*)d_in[5];
    const float* W2     = (const float*)d_in[6];
    const float* b2     = (const float*)d_in[7];
    float* out = (float*)d_out;

    const int N = in_sizes[0];          // 8192 * 978 = 8,011,776
    const int Brows = N / NGENES;       // 8192
    const int E = in_sizes[1] / 2;      // 20,000,000

    char* ws = (char*)d_ws;
    size_t off = 0;
    auto carve = [&](size_t bytes) -> void* {
        void* p = ws + off;
        off = (off + bytes + 255) & ~(size_t)255;
        return p;
    };
    u16*   Abf = (u16*)carve((size_t)Brows * KPAD * 2);
    u16*   W1T = (u16*)carve((size_t)H1DIM * KPAD * 2);
    u16*   W2Tp = (u16*)carve((size_t)NOUTP * H1DIM * 2);
    u16*   H1  = (u16*)carve((size_t)Brows * H1DIM * 2);
    int*   flag = (int*)carve(256);
    // binned-scatter extras
    u16*   xb     = (u16*)carve((size_t)N * 2);
    u32*   hist   = (u32*)carve((size_t)NWG_BIN * HSTRIDE * 4);
    u32*   totals = (u32*)carve((size_t)NB * 4);
    u32*   bases  = (u32*)carve((size_t)(NB + 1) * 4);
    u32*   pairs  = (u32*)carve((size_t)E * 4);
    float* agg    = (float*)carve((size_t)N * 4);   // fallback only
    const bool use_binned = (off - ((size_t)N * 4 + 256) <= ws_size) &&
                            ((size_t)((char*)agg - ws) <= ws_size);

    hipMemsetAsync(out, 0, (size_t)out_size * 4, stream);
    detect_kernel<<<1, 64, 0, stream>>>((const unsigned*)edges, flag);

    if (use_binned) {
        xbf_kernel<<<(N / 4 + 255) / 256, 256, 0, stream>>>(inputs, gcn_w, xb, N);
        hist_kernel<<<NWG_BIN, BTHR, 0, stream>>>(edges, flag, E, hist);
        scan_col_kernel<<<(NB + 255) / 256, 256, 0, stream>>>(hist, totals);
        scan_bucket_kernel<<<1, 64, 0, stream>>>(totals, bases);
        binscatter_kernel<<<NWG_BIN, BTHR, 0, stream>>>(edges, xb, flag, E,
                                                        hist, bases, pairs);
        accum_kernel<<<NB, 512, 0, stream>>>(pairs, bases, gcn_b, Abf);
        pad_kernel<<<(Brows * (KPAD - NGENES) + 255) / 256, 256, 0, stream>>>(Abf, Brows);
    } else {
        hipMemsetAsync(agg, 0, (size_t)N * 4, stream);
        const int sblocks = (E + 255) / 256;
        scatter_kernel<<<sblocks, 256, 0, stream>>>(edges, inputs, gcn_w, agg, flag, E);
        act_kernel<<<(Brows * KPAD) / 256, 256, 0, stream>>>(agg, gcn_b, Abf);
    }

    transposeW1<<<dim3(H1DIM / 32, KPAD / 32), dim3(32, 8), 0, stream>>>(W1, W1T);
    transposeW2<<<dim3(4, H1DIM / 32), dim3(32, 8), 0, stream>>>(W2, W2Tp);

    gemm1_kernel<<<dim3(H1DIM / 128, Brows / 128), 256, 0, stream>>>(Abf, W1T, b1, H1);
    gemm2_kernel<<<dim3(KSPLIT, Brows / 64), 256, 0, stream>>>(H1, W2Tp, b2, out);
}

// Round 5
// 1034.039 us; speedup vs baseline: 1.0309x; 1.0309x over previous
//
#include <hip/hip_runtime.h>
#include <hip/hip_bf16.h>
#include <stdint.h>

// ---------------------------------------------------------------------------
// GCN encoder: two-phase binned scatter-add -> relu -> GEMM1(978->2048)+relu
// -> GEMM2(2048->100). bf16 MFMA GEMMs (fp32 accumulate).
//
// R5 scatter: phase A bins edges by src (8 bins = 2MB xb slices) -> phase B
// (bin = blockIdx%8 ~ XCD) gathers from L2-resident slice and bins by dst
// into 489 coarse buckets (31K write streams/XCD < 64K L2 lines, no
// write-amp) -> accum in 64KB LDS tiles with fused bias/relu/bf16 epilogue.
// ---------------------------------------------------------------------------

typedef unsigned short u16;
typedef unsigned int u32;
typedef unsigned long long u64;
typedef __bf16 bf16x8 __attribute__((ext_vector_type(8)));
typedef float f32x4 __attribute__((ext_vector_type(4)));

#define NGENES 978
#define KPAD   1024
#define H1DIM  2048
#define NOUT   100
#define NOUTP  112
#define KSPLIT 2

// scatter constants
#define SB       8       // src bins (bin = src >> 20, 2MB bf16 slice)
#define SRCSH    20
#define BSH      14      // dst bucket shift: 16384-node tiles (64KB fp32 LDS)
#define TILE     16384
#define NBKT_MAX 512     // >= ceil(N/TILE) = 489
#define NWG_A    1024
#define NWG_B    512     // 64 per src-bin; blockIdx%8 -> src bin (XCD affinity)

__device__ __forceinline__ u16 f2b(float f) {
    unsigned u = __builtin_bit_cast(unsigned, f);
    u = (u + 0x7FFFu + ((u >> 16) & 1u)) >> 16;
    return (u16)u;
}

__device__ __forceinline__ void gl2lds16(const void* g, void* l) {
    __builtin_amdgcn_global_load_lds(
        (const __attribute__((address_space(1))) void*)(uintptr_t)g,
        (__attribute__((address_space(3))) void*)(unsigned)(uintptr_t)l,
        16, 0, 0);
}

template <typename T>
__device__ __forceinline__ T ntl(const T* p) { return __builtin_nontemporal_load(p); }

// ---------------------------------------------------------------------------
__global__ void detect_kernel(const unsigned* __restrict__ e, int* __restrict__ flag) {
    if (threadIdx.x == 0) {
        int is64 = 1;
        for (int i = 0; i < 64; ++i)
            if (e[2 * i + 1] != 0u) { is64 = 0; break; }
        *flag = is64;
    }
}

// xb[n] = bf16(inputs[n] * gcn_w) — 16 MB gather table
__global__ void xbf_kernel(const float* __restrict__ x, const float* __restrict__ gcn_w,
                           u16* __restrict__ xb, int N) {
    const float w = gcn_w[0];
    int i = (blockIdx.x * 256 + threadIdx.x) * 4;
    if (i + 3 < N) {
        float4 v = *(const float4*)&x[i];
        xb[i + 0] = f2b(v.x * w);
        xb[i + 1] = f2b(v.y * w);
        xb[i + 2] = f2b(v.z * w);
        xb[i + 3] = f2b(v.w * w);
    } else {
        for (int k = i; k < N; ++k) xb[k] = f2b(x[k] * w);
    }
}

// ---------------------------------------------------------------------------
// Phase A hist: per-WG counts of src bins. histA[wg*SB + b].
// ---------------------------------------------------------------------------
__global__ __launch_bounds__(512) void histA_kernel(const void* __restrict__ edges,
                                                    const int* __restrict__ flag, int E,
                                                    u32* __restrict__ histA) {
    __shared__ u32 h[8][SB];   // per-wave counters to cut same-address contention
    const int tid = threadIdx.x, wv = tid >> 6;
    if (tid < 8 * SB) ((u32*)h)[tid] = 0;
    __syncthreads();
    const int wg = blockIdx.x;
    const int per = (E + NWG_A - 1) / NWG_A;
    const int s = wg * per, e = min(E, s + per);
    int i = s + tid;
    if (*flag) {
        const u64* es = (const u64*)edges;
        for (; i + 7 * 512 < e; i += 8 * 512) {
            u32 sv[8];
#pragma unroll
            for (int k = 0; k < 8; ++k) sv[k] = (u32)ntl(es + i + k * 512);
#pragma unroll
            for (int k = 0; k < 8; ++k) atomicAdd(&h[wv][sv[k] >> SRCSH], 1u);
        }
        for (; i < e; i += 512) atomicAdd(&h[wv][(u32)ntl(es + i) >> SRCSH], 1u);
    } else {
        const u32* es = (const u32*)edges;
        for (; i + 7 * 512 < e; i += 8 * 512) {
            u32 sv[8];
#pragma unroll
            for (int k = 0; k < 8; ++k) sv[k] = ntl(es + i + k * 512);
#pragma unroll
            for (int k = 0; k < 8; ++k) atomicAdd(&h[wv][sv[k] >> SRCSH], 1u);
        }
        for (; i < e; i += 512) atomicAdd(&h[wv][ntl(es + i) >> SRCSH], 1u);
    }
    __syncthreads();
    if (tid < SB) {
        u32 t = 0;
#pragma unroll
        for (int w = 0; w < 8; ++w) t += h[w][tid];
        histA[wg * SB + tid] = t;
    }
}

// ---------------------------------------------------------------------------
// scanA: per-bin exclusive scan over NWG_A rows (in place) + basesA[0..SB].
// One block of 1024 threads (= NWG_A rows).
// ---------------------------------------------------------------------------
__global__ __launch_bounds__(1024) void scanA_kernel(u32* __restrict__ histA,
                                                     u32* __restrict__ basesA) {
    __shared__ u32 ws[16], wso[16], tot[SB];
    const int t = threadIdx.x, lane = t & 63, wv = t >> 6;
    for (int b = 0; b < SB; ++b) {
        u32 v = histA[t * SB + b];
        u32 incl = v;
#pragma unroll
        for (int o = 1; o < 64; o <<= 1) {
            u32 x = __shfl_up(incl, o, 64);
            if (lane >= o) incl += x;
        }
        if (lane == 63) ws[wv] = incl;
        __syncthreads();
        if (t == 0) {
            u32 r = 0;
#pragma unroll
            for (int i = 0; i < 16; ++i) { wso[i] = r; r += ws[i]; }
            tot[b] = r;
        }
        __syncthreads();
        histA[t * SB + b] = wso[wv] + incl - v;
        __syncthreads();
    }
    if (t == 0) {
        u32 r = 0;
        for (int b = 0; b < SB; ++b) { basesA[b] = r; r += tot[b]; }
        basesA[SB] = r;
    }
}

// ---------------------------------------------------------------------------
// Phase A scatter: edges -> (srcA, dstA) SoA grouped by src bin.
// ---------------------------------------------------------------------------
__global__ __launch_bounds__(512) void binA_kernel(const void* __restrict__ edges,
                                                   const int* __restrict__ flag, int E,
                                                   const u32* __restrict__ histA,
                                                   const u32* __restrict__ basesA,
                                                   u32* __restrict__ srcA, u32* __restrict__ dstA) {
    __shared__ u32 cur[SB];
    const int wg = blockIdx.x, tid = threadIdx.x;
    if (tid < SB) cur[tid] = basesA[tid] + histA[wg * SB + tid];
    __syncthreads();
    const int per = (E + NWG_A - 1) / NWG_A;
    const int s = wg * per, e = min(E, s + per);
    int i = s + tid;
    if (*flag) {
        const u64* es = (const u64*)edges;
        const u64* ed = es + E;
        for (; i + 7 * 512 < e; i += 8 * 512) {
            u32 sv[8], dv[8];
#pragma unroll
            for (int k = 0; k < 8; ++k) sv[k] = (u32)ntl(es + i + k * 512);
#pragma unroll
            for (int k = 0; k < 8; ++k) dv[k] = (u32)ntl(ed + i + k * 512);
#pragma unroll
            for (int k = 0; k < 8; ++k) {
                u32 p = atomicAdd(&cur[sv[k] >> SRCSH], 1u);
                srcA[p] = sv[k];
                dstA[p] = dv[k];
            }
        }
        for (; i < e; i += 512) {
            u32 sv = (u32)ntl(es + i), dv = (u32)ntl(ed + i);
            u32 p = atomicAdd(&cur[sv >> SRCSH], 1u);
            srcA[p] = sv;
            dstA[p] = dv;
        }
    } else {
        const u32* es = (const u32*)edges;
        const u32* ed = es + E;
        for (; i + 7 * 512 < e; i += 8 * 512) {
            u32 sv[8], dv[8];
#pragma unroll
            for (int k = 0; k < 8; ++k) sv[k] = ntl(es + i + k * 512);
#pragma unroll
            for (int k = 0; k < 8; ++k) dv[k] = ntl(ed + i + k * 512);
#pragma unroll
            for (int k = 0; k < 8; ++k) {
                u32 p = atomicAdd(&cur[sv[k] >> SRCSH], 1u);
                srcA[p] = sv[k];
                dstA[p] = dv[k];
            }
        }
        for (; i < e; i += 512) {
            u32 sv = ntl(es + i), dv = ntl(ed + i);
            u32 p = atomicAdd(&cur[sv >> SRCSH], 1u);
            srcA[p] = sv;
            dstA[p] = dv;
        }
    }
}

// chunk bounds for phase-B WG w over src-binned arrays
__device__ __forceinline__ void chunkB(const u32* __restrict__ basesA, int w, int& lo, int& hi) {
    const int bin = w & (SB - 1), c = w >> 3;
    const u32 s0 = basesA[bin], s1 = basesA[bin + 1];
    const u32 csz = (s1 - s0 + (NWG_B / SB) - 1) / (NWG_B / SB);
    u32 l = s0 + (u32)c * csz;
    u32 h = l + csz;
    if (l > s1) l = s1;
    if (h > s1) h = s1;
    lo = (int)l; hi = (int)h;
}

// ---------------------------------------------------------------------------
// Phase B hist: per-WG counts of dst buckets over its src-binned chunk.
// histB[w * NBKT_MAX + b].
// ---------------------------------------------------------------------------
__global__ __launch_bounds__(512) void histB_kernel(const u32* __restrict__ dstA,
                                                    const u32* __restrict__ basesA,
                                                    u32* __restrict__ histB) {
    __shared__ u32 h[NBKT_MAX];
    const int tid = threadIdx.x, w = blockIdx.x;
    for (int b = tid; b < NBKT_MAX; b += 512) h[b] = 0;
    __syncthreads();
    int lo, hi;
    chunkB(basesA, w, lo, hi);
    int i = lo + tid;
    for (; i + 7 * 512 < hi; i += 8 * 512) {
        u32 d[8];
#pragma unroll
        for (int k = 0; k < 8; ++k) d[k] = ntl(dstA + i + k * 512);
#pragma unroll
        for (int k = 0; k < 8; ++k) atomicAdd(&h[d[k] >> BSH], 1u);
    }
    for (; i < hi; i += 512) atomicAdd(&h[ntl(dstA + i) >> BSH], 1u);
    __syncthreads();
    for (int b = tid; b < NBKT_MAX; b += 512) histB[(size_t)w * NBKT_MAX + b] = h[b];
}

// ---------------------------------------------------------------------------
// Tier-2 variant: hist of dst buckets straight from edges (chunk = edge range).
// ---------------------------------------------------------------------------
__global__ __launch_bounds__(512) void histE_kernel(const void* __restrict__ edges,
                                                    const int* __restrict__ flag, int E,
                                                    u32* __restrict__ histB) {
    __shared__ u32 h[NBKT_MAX];
    const int tid = threadIdx.x, w = blockIdx.x;
    for (int b = tid; b < NBKT_MAX; b += 512) h[b] = 0;
    __syncthreads();
    const int per = (E + NWG_B - 1) / NWG_B;
    const int s = w * per, e = min(E, s + per);
    int i = s + tid;
    if (*flag) {
        const u64* ed = (const u64*)edges + E;
        for (; i + 7 * 512 < e; i += 8 * 512) {
            u32 d[8];
#pragma unroll
            for (int k = 0; k < 8; ++k) d[k] = (u32)ntl(ed + i + k * 512);
#pragma unroll
            for (int k = 0; k < 8; ++k) atomicAdd(&h[d[k] >> BSH], 1u);
        }
        for (; i < e; i += 512) atomicAdd(&h[(u32)ntl(ed + i) >> BSH], 1u);
    } else {
        const u32* ed = (const u32*)edges + E;
        for (; i + 7 * 512 < e; i += 8 * 512) {
            u32 d[8];
#pragma unroll
            for (int k = 0; k < 8; ++k) d[k] = ntl(ed + i + k * 512);
#pragma unroll
            for (int k = 0; k < 8; ++k) atomicAdd(&h[d[k] >> BSH], 1u);
        }
        for (; i < e; i += 512) atomicAdd(&h[ntl(ed + i) >> BSH], 1u);
    }
    __syncthreads();
    for (int b = tid; b < NBKT_MAX; b += 512) histB[(size_t)w * NBKT_MAX + b] = h[b];
}

// column scan of histB over NWG_B rows (in place) + totalsB
__global__ __launch_bounds__(256) void scanBcol_kernel(u32* __restrict__ histB,
                                                       u32* __restrict__ totalsB, int nbkt) {
    const int b = blockIdx.x * 256 + threadIdx.x;
    const bool act = b < nbkt;
    u32 run = 0;
    for (int w = 0; w < NWG_B; ++w) {
        size_t idx = (size_t)w * NBKT_MAX + b;
        u32 v = act ? histB[idx] : 0;
        if (act) histB[idx] = run;
        run += v;
    }
    if (act) totalsB[b] = run;
}

// exclusive scan of bucket totals -> basesB[0..nbkt]
__global__ void scanBbase_kernel(const u32* __restrict__ totalsB, u32* __restrict__ basesB,
                                 int nbkt) {
    const int lane = threadIdx.x;
    u32 running = 0;
    const int iters = (nbkt + 63) / 64;
    for (int it = 0; it < iters; ++it) {
        int idx = it * 64 + lane;
        u32 v = (idx < nbkt) ? totalsB[idx] : 0;
        u32 incl = v;
#pragma unroll
        for (int off = 1; off < 64; off <<= 1) {
            u32 t = __shfl_up(incl, off, 64);
            if (lane >= off) incl += t;
        }
        if (idx < nbkt) basesB[idx] = running + incl - v;
        running += __shfl(incl, 63, 64);
    }
    if (lane == 0) basesB[nbkt] = running;
}

// ---------------------------------------------------------------------------
// Phase B: gather from L2-resident xb slice (bin = blockIdx%8 ~ XCD), bin by
// dst into pairs = (dst_local << 16) | bf16val.
// ---------------------------------------------------------------------------
__global__ __launch_bounds__(512) void binB_kernel(const u32* __restrict__ srcA,
                                                   const u32* __restrict__ dstA,
                                                   const u16* __restrict__ xb,
                                                   const u32* __restrict__ basesA,
                                                   const u32* __restrict__ histB,
                                                   const u32* __restrict__ basesB,
                                                   u32* __restrict__ pairs, int nbkt) {
    __shared__ u32 cur[NBKT_MAX];
    const int tid = threadIdx.x, w = blockIdx.x;
    for (int b = tid; b < nbkt; b += 512) cur[b] = basesB[b] + histB[(size_t)w * NBKT_MAX + b];
    __syncthreads();
    int lo, hi;
    chunkB(basesA, w, lo, hi);
    int i = lo + tid;
    for (; i + 7 * 512 < hi; i += 8 * 512) {
        u32 sv[8], dv[8];
        u16 val[8];
#pragma unroll
        for (int k = 0; k < 8; ++k) sv[k] = ntl(srcA + i + k * 512);
#pragma unroll
        for (int k = 0; k < 8; ++k) dv[k] = ntl(dstA + i + k * 512);
#pragma unroll
        for (int k = 0; k < 8; ++k) val[k] = xb[sv[k]];     // cached, L2-resident slice
#pragma unroll
        for (int k = 0; k < 8; ++k) {
            u32 pos = atomicAdd(&cur[dv[k] >> BSH], 1u);
            pairs[pos] = ((dv[k] & (TILE - 1)) << 16) | (u32)val[k];
        }
    }
    for (; i < hi; i += 512) {
        u32 sv = ntl(srcA + i), dv = ntl(dstA + i);
        u16 v = xb[sv];
        u32 pos = atomicAdd(&cur[dv >> BSH], 1u);
        pairs[pos] = ((dv & (TILE - 1)) << 16) | (u32)v;
    }
}

// ---------------------------------------------------------------------------
// Tier-2: single-phase binscatter straight from edges (random gather).
// ---------------------------------------------------------------------------
__global__ __launch_bounds__(512) void binE_kernel(const void* __restrict__ edges,
                                                   const u16* __restrict__ xb,
                                                   const int* __restrict__ flag, int E,
                                                   const u32* __restrict__ histB,
                                                   const u32* __restrict__ basesB,
                                                   u32* __restrict__ pairs, int nbkt) {
    __shared__ u32 cur[NBKT_MAX];
    const int tid = threadIdx.x, w = blockIdx.x;
    for (int b = tid; b < nbkt; b += 512) cur[b] = basesB[b] + histB[(size_t)w * NBKT_MAX + b];
    __syncthreads();
    const int per = (E + NWG_B - 1) / NWG_B;
    const int s = w * per, e = min(E, s + per);
    int i = s + tid;
    if (*flag) {
        const u64* es = (const u64*)edges;
        const u64* ed = es + E;
        for (; i + 7 * 512 < e; i += 8 * 512) {
            u32 sv[8], dv[8];
            u16 val[8];
#pragma unroll
            for (int k = 0; k < 8; ++k) sv[k] = (u32)ntl(es + i + k * 512);
#pragma unroll
            for (int k = 0; k < 8; ++k) dv[k] = (u32)ntl(ed + i + k * 512);
#pragma unroll
            for (int k = 0; k < 8; ++k) val[k] = xb[sv[k]];
#pragma unroll
            for (int k = 0; k < 8; ++k) {
                u32 pos = atomicAdd(&cur[dv[k] >> BSH], 1u);
                pairs[pos] = ((dv[k] & (TILE - 1)) << 16) | (u32)val[k];
            }
        }
        for (; i < e; i += 512) {
            u32 sv = (u32)ntl(es + i), dv = (u32)ntl(ed + i);
            u16 v = xb[sv];
            u32 pos = atomicAdd(&cur[dv >> BSH], 1u);
            pairs[pos] = ((dv & (TILE - 1)) << 16) | (u32)v;
        }
    } else {
        const u32* es = (const u32*)edges;
        const u32* ed = es + E;
        for (; i + 7 * 512 < e; i += 8 * 512) {
            u32 sv[8], dv[8];
            u16 val[8];
#pragma unroll
            for (int k = 0; k < 8; ++k) sv[k] = ntl(es + i + k * 512);
#pragma unroll
            for (int k = 0; k < 8; ++k) dv[k] = ntl(ed + i + k * 512);
#pragma unroll
            for (int k = 0; k < 8; ++k) val[k] = xb[sv[k]];
#pragma unroll
            for (int k = 0; k < 8; ++k) {
                u32 pos = atomicAdd(&cur[dv[k] >> BSH], 1u);
                pairs[pos] = ((dv[k] & (TILE - 1)) << 16) | (u32)val[k];
            }
        }
        for (; i < e; i += 512) {
            u32 sv = ntl(es + i), dv = ntl(ed + i);
            u16 v = xb[sv];
            u32 pos = atomicAdd(&cur[dv >> BSH], 1u);
            pairs[pos] = ((dv & (TILE - 1)) << 16) | (u32)v;
        }
    }
}

// ---------------------------------------------------------------------------
// accum: 64KB LDS fp32 tile per bucket + fused bias/relu/bf16/KPAD epilogue.
// ---------------------------------------------------------------------------
__global__ __launch_bounds__(512) void accum_kernel(const u32* __restrict__ pairs,
                                                    const u32* __restrict__ basesB,
                                                    const float* __restrict__ gcn_b,
                                                    u16* __restrict__ A, int Ntot) {
    __shared__ float acc[TILE];   // 64 KB
    const int tid = threadIdx.x, b = blockIdx.x;
    for (int i = tid; i < TILE; i += 512) acc[i] = 0.f;
    __syncthreads();
    const u32 p0 = basesB[b], p1 = basesB[b + 1];
    u32 p = p0 + tid;
    for (; p + 3 * 512 < p1; p += 4 * 512) {
        u32 pk[4];
#pragma unroll
        for (int k = 0; k < 4; ++k) pk[k] = ntl(pairs + p + k * 512);
#pragma unroll
        for (int k = 0; k < 4; ++k) {
            float v = __builtin_bit_cast(float, (pk[k] & 0xFFFFu) << 16);
            atomicAdd(&acc[pk[k] >> 16], v);
        }
    }
    for (; p < p1; p += 512) {
        u32 pk = ntl(pairs + p);
        float v = __builtin_bit_cast(float, (pk & 0xFFFFu) << 16);
        atomicAdd(&acc[pk >> 16], v);
    }
    __syncthreads();
    const float bias = gcn_b[0];
    const u32 n0 = (u32)b << BSH;
    for (int i = tid; i < TILE; i += 512) {
        u32 n = n0 + i;
        if (n < (u32)Ntot) {
            u32 row = n / NGENES;
            u32 g = n - row * NGENES;
            float v = acc[i] + bias;
            v = v > 0.f ? v : 0.f;
            A[(size_t)row * KPAD + g] = f2b(v);
        }
    }
}

// Zero the K-pad columns A[:, 978:1024].
__global__ void pad_kernel(u16* __restrict__ A, int Brows) {
    int idx = blockIdx.x * 256 + threadIdx.x;
    int row = idx / (KPAD - NGENES);
    int k = idx - row * (KPAD - NGENES);
    if (row < Brows) A[(size_t)row * KPAD + NGENES + k] = 0;
}

// ---------------------------------------------------------------------------
// Tier-3 legacy path.
// ---------------------------------------------------------------------------
__global__ void scatter_kernel(const void* __restrict__ edges, const float* __restrict__ x,
                               const float* __restrict__ gcn_w, float* __restrict__ agg,
                               const int* __restrict__ flag, int E) {
    long long e = (long long)blockIdx.x * 256 + threadIdx.x;
    if (e >= E) return;
    int s, d;
    if (*flag) {
        const long long* e64 = (const long long*)edges;
        s = (int)e64[e];
        d = (int)e64[(long long)E + e];
    } else {
        const int* e32 = (const int*)edges;
        s = e32[e];
        d = e32[(long long)E + e];
    }
    atomicAdd(&agg[d], x[s] * gcn_w[0]);
}

__global__ void act_kernel(const float* __restrict__ agg, const float* __restrict__ gcn_b,
                           u16* __restrict__ A) {
    int idx = blockIdx.x * 256 + threadIdx.x;
    int i = idx >> 10;
    int k = idx & 1023;
    float v = 0.f;
    if (k < NGENES) {
        v = agg[(size_t)i * NGENES + k] + gcn_b[0];
        v = v > 0.f ? v : 0.f;
    }
    A[idx] = f2b(v);
}

// ---------------------------------------------------------------------------
// W1 [978][2048] f32 -> W1T [2048][1024] bf16
// ---------------------------------------------------------------------------
__global__ void transposeW1(const float* __restrict__ W1, u16* __restrict__ W1T) {
    __shared__ float t[32][33];
    int n0 = blockIdx.x * 32;
    int k0 = blockIdx.y * 32;
    int tx = threadIdx.x, ty = threadIdx.y;
    for (int r = ty; r < 32; r += 8) {
        int k = k0 + r;
        t[r][tx] = (k < NGENES) ? W1[(size_t)k * H1DIM + n0 + tx] : 0.f;
    }
    __syncthreads();
    for (int r = ty; r < 32; r += 8) {
        int n = n0 + r;
        W1T[(size_t)n * KPAD + k0 + tx] = f2b(t[tx][r]);
    }
}

// W2 [2048][100] f32 -> W2T [112][2048] bf16
__global__ void transposeW2(const float* __restrict__ W2, u16* __restrict__ W2T) {
    __shared__ float t[32][33];
    int n0 = blockIdx.x * 32;
    int k0 = blockIdx.y * 32;
    int tx = threadIdx.x, ty = threadIdx.y;
    for (int r = ty; r < 32; r += 8) {
        int k = k0 + r;
        int n = n0 + tx;
        t[r][tx] = (n < NOUT) ? W2[(size_t)k * NOUT + n] : 0.f;
    }
    __syncthreads();
    for (int r = ty; r < 32; r += 8) {
        int n = n0 + r;
        if (n < NOUTP) W2T[(size_t)n * H1DIM + k0 + tx] = f2b(t[tx][r]);
    }
}

// ---------------------------------------------------------------------------
// GEMM1: H = relu(A[8192][1024] @ W1T^T + b1), bf16 out. 128x128 tile.
// ---------------------------------------------------------------------------
__global__ __launch_bounds__(256) void gemm1_kernel(const u16* __restrict__ A,
                                                    const u16* __restrict__ Bt,
                                                    const float* __restrict__ b1,
                                                    u16* __restrict__ H) {
    __shared__ u16 As[128 * 32];
    __shared__ u16 Bs[128 * 32];
    const int tid = threadIdx.x;
    const int m0 = blockIdx.y * 128;
    const int n0 = blockIdx.x * 128;
    const int wave = tid >> 6;
    const int lane = tid & 63;
    const int wm = (wave >> 1) * 64;
    const int wn = (wave & 1) * 64;
    const int quad = lane >> 4;
    const int l16 = lane & 15;

    f32x4 acc[4][4];
#pragma unroll
    for (int i = 0; i < 4; ++i)
#pragma unroll
        for (int j = 0; j < 4; ++j)
            acc[i][j] = (f32x4){0.f, 0.f, 0.f, 0.f};

    const int ch0 = tid, ch1 = tid + 256;
    const u16* ag0 = A + (size_t)(m0 + (ch0 >> 2)) * KPAD + (ch0 & 3) * 8;
    const u16* ag1 = A + (size_t)(m0 + (ch1 >> 2)) * KPAD + (ch1 & 3) * 8;
    const u16* bg0 = Bt + (size_t)(n0 + (ch0 >> 2)) * KPAD + (ch0 & 3) * 8;
    const u16* bg1 = Bt + (size_t)(n0 + (ch1 >> 2)) * KPAD + (ch1 & 3) * 8;
    u16* la0 = &As[ch0 * 8];
    u16* la1 = &As[ch1 * 8];
    u16* lb0 = &Bs[ch0 * 8];
    u16* lb1 = &Bs[ch1 * 8];

    for (int k0 = 0; k0 < KPAD; k0 += 32) {
        gl2lds16(ag0, la0);
        gl2lds16(ag1, la1);
        gl2lds16(bg0, lb0);
        gl2lds16(bg1, lb1);
        ag0 += 32; ag1 += 32; bg0 += 32; bg1 += 32;
        __syncthreads();

        bf16x8 af[4], bfr[4];
#pragma unroll
        for (int i = 0; i < 4; ++i)
            af[i] = *(const bf16x8*)&As[(wm + i * 16 + l16) * 32 + quad * 8];
#pragma unroll
        for (int j = 0; j < 4; ++j)
            bfr[j] = *(const bf16x8*)&Bs[(wn + j * 16 + l16) * 32 + quad * 8];
#pragma unroll
        for (int i = 0; i < 4; ++i)
#pragma unroll
            for (int j = 0; j < 4; ++j)
                acc[i][j] = __builtin_amdgcn_mfma_f32_16x16x32_bf16(af[i], bfr[j], acc[i][j], 0, 0, 0);
        __syncthreads();
    }

#pragma unroll
    for (int j = 0; j < 4; ++j) {
        const int col = n0 + wn + j * 16 + l16;
        const float bv = b1[col];
#pragma unroll
        for (int i = 0; i < 4; ++i) {
            const int rbase = m0 + wm + i * 16 + quad * 4;
#pragma unroll
            for (int r = 0; r < 4; ++r) {
                float v = acc[i][j][r] + bv;
                v = v > 0.f ? v : 0.f;
                H[(size_t)(rbase + r) * H1DIM + col] = f2b(v);
            }
        }
    }
}

// ---------------------------------------------------------------------------
// GEMM2: out += H @ W2T^T + b2, split-K=2 with atomics.
// ---------------------------------------------------------------------------
__global__ __launch_bounds__(256) void gemm2_kernel(const u16* __restrict__ Hh,
                                                    const u16* __restrict__ W2T,
                                                    const float* __restrict__ b2,
                                                    float* __restrict__ out) {
    __shared__ u16 As[64 * 32];
    __shared__ u16 Bs[NOUTP * 32];
    const int tid = threadIdx.x;
    const int m0 = blockIdx.y * 64;
    const int kc = blockIdx.x;
    const int kbase = kc * (H1DIM / KSPLIT);
    const int wave = tid >> 6;
    const int lane = tid & 63;
    const int quad = lane >> 4;
    const int l16 = lane & 15;

    f32x4 acc[7];
#pragma unroll
    for (int j = 0; j < 7; ++j) acc[j] = (f32x4){0.f, 0.f, 0.f, 0.f};

    const u16* ag = Hh + (size_t)(m0 + (tid >> 2)) * H1DIM + kbase + (tid & 3) * 8;
    u16* la = &As[tid * 8];
    const u16* bg0 = W2T + (size_t)(tid >> 2) * H1DIM + kbase + (tid & 3) * 8;
    u16* lb0 = &Bs[tid * 8];
    const int ch1 = tid + 256;
    const u16* bg1 = W2T + (size_t)(ch1 >> 2) * H1DIM + kbase + (ch1 & 3) * 8;
    u16* lb1 = &Bs[ch1 * 8];
    const bool bact = (ch1 < NOUTP * 4);

    for (int kk = 0; kk < H1DIM / KSPLIT; kk += 32) {
        gl2lds16(ag, la);
        gl2lds16(bg0, lb0);
        if (bact) gl2lds16(bg1, lb1);
        ag += 32; bg0 += 32; bg1 += 32;
        __syncthreads();

        bf16x8 af = *(const bf16x8*)&As[(wave * 16 + l16) * 32 + quad * 8];
#pragma unroll
        for (int j = 0; j < 7; ++j) {
            bf16x8 bfr = *(const bf16x8*)&Bs[(j * 16 + l16) * 32 + quad * 8];
            acc[j] = __builtin_amdgcn_mfma_f32_16x16x32_bf16(af, bfr, acc[j], 0, 0, 0);
        }
        __syncthreads();
    }

#pragma unroll
    for (int j = 0; j < 7; ++j) {
        const int col = j * 16 + l16;
        if (col < NOUT) {
            const float bv = (kc == 0) ? b2[col] : 0.f;
            const int rbase = m0 + wave * 16 + quad * 4;
#pragma unroll
            for (int r = 0; r < 4; ++r)
                atomicAdd(&out[(size_t)(rbase + r) * NOUT + col], acc[j][r] + bv);
        }
    }
}

// ---------------------------------------------------------------------------
extern "C" void kernel_launch(void* const* d_in, const int* in_sizes, int n_in,
                              void* d_out, int out_size, void* d_ws, size_t ws_size,
                              hipStream_t stream) {
    const float* inputs = (const float*)d_in[0];
    const void*  edges  = d_in[1];
    const float* gcn_w  = (const float*)d_in[2];
    const float* gcn_b  = (const float*)d_in[3];
    const float* W1     = (const float*)d_in[4];
    const float* b1     = (const float*)d_in[5];
    const float* W2     = (const float*)d_in[6];
    const float* b2     = (const float*)d_in[7];
    float* out = (float*)d_out;

    const int N = in_sizes[0];          // 8,011,776
    const int Brows = N / NGENES;       // 8192
    const int E = in_sizes[1] / 2;      // 20,000,000
    const int nbkt = (N + TILE - 1) / TILE;   // 489

    char* ws = (char*)d_ws;
    size_t off = 0;
    auto carve = [&](size_t bytes) -> void* {
        void* p = ws + off;
        off = (off + bytes + 255) & ~(size_t)255;
        return p;
    };
    // fixed region
    u16* Abf   = (u16*)carve((size_t)Brows * KPAD * 2);
    u16* W1T   = (u16*)carve((size_t)H1DIM * KPAD * 2);
    u16* W2Tp  = (u16*)carve((size_t)NOUTP * H1DIM * 2);
    int* flag  = (int*)carve(256);
    u16* xb    = (u16*)carve((size_t)N * 2);
    u32* histA = (u32*)carve((size_t)NWG_A * SB * 4);
    u32* histB = (u32*)carve((size_t)NWG_B * NBKT_MAX * 4);
    u32* totB  = (u32*)carve((size_t)NBKT_MAX * 4);
    u32* basesA = (u32*)carve((size_t)(SB + 1) * 4);
    u32* basesB = (u32*)carve((size_t)(NBKT_MAX + 1) * 4);
    const size_t mark = off;

    // tier-1 layout: srcA + dstA + pairs; H1 aliases srcA (dead before gemm1)
    u32* srcA = (u32*)carve((size_t)E * 4);
    u32* dstA = (u32*)carve((size_t)E * 4);
    u32* pairs1 = (u32*)carve((size_t)E * 4);
    const size_t need1 = off;
    // tier-2 layout: pairs at mark; H1 aliases pairs (dead before gemm1)
    const size_t need2 = mark + ((size_t)E * 4 + 255 & ~(size_t)255);
    // tier-3: agg at mark; H1 aliases agg
    const size_t need3 = mark + ((size_t)N * 4 + 255 & ~(size_t)255);

    int tier = (need1 <= ws_size) ? 1 : (need2 <= ws_size) ? 2 : 3;
    u16* H1;
    if (tier == 1)      H1 = (u16*)srcA;
    else                H1 = (u16*)(ws + mark);

    hipMemsetAsync(out, 0, (size_t)out_size * 4, stream);
    detect_kernel<<<1, 64, 0, stream>>>((const unsigned*)edges, flag);

    if (tier == 1) {
        xbf_kernel<<<(N / 4 + 255) / 256, 256, 0, stream>>>(inputs, gcn_w, xb, N);
        histA_kernel<<<NWG_A, 512, 0, stream>>>(edges, flag, E, histA);
        scanA_kernel<<<1, 1024, 0, stream>>>(histA, basesA);
        binA_kernel<<<NWG_A, 512, 0, stream>>>(edges, flag, E, histA, basesA, srcA, dstA);
        histB_kernel<<<NWG_B, 512, 0, stream>>>(dstA, basesA, histB);
        scanBcol_kernel<<<(nbkt + 255) / 256, 256, 0, stream>>>(histB, totB, nbkt);
        scanBbase_kernel<<<1, 64, 0, stream>>>(totB, basesB, nbkt);
        binB_kernel<<<NWG_B, 512, 0, stream>>>(srcA, dstA, xb, basesA, histB, basesB,
                                               pairs1, nbkt);
        accum_kernel<<<nbkt, 512, 0, stream>>>(pairs1, basesB, gcn_b, Abf, N);
        pad_kernel<<<(Brows * (KPAD - NGENES) + 255) / 256, 256, 0, stream>>>(Abf, Brows);
    } else if (tier == 2) {
        u32* pairs = (u32*)(ws + mark);
        xbf_kernel<<<(N / 4 + 255) / 256, 256, 0, stream>>>(inputs, gcn_w, xb, N);
        histE_kernel<<<NWG_B, 512, 0, stream>>>(edges, flag, E, histB);
        scanBcol_kernel<<<(nbkt + 255) / 256, 256, 0, stream>>>(histB, totB, nbkt);
        scanBbase_kernel<<<1, 64, 0, stream>>>(totB, basesB, nbkt);
        binE_kernel<<<NWG_B, 512, 0, stream>>>(edges, xb, flag, E, histB, basesB,
                                               pairs, nbkt);
        accum_kernel<<<nbkt, 512, 0, stream>>>(pairs, basesB, gcn_b, Abf, N);
        pad_kernel<<<(Brows * (KPAD - NGENES) + 255) / 256, 256, 0, stream>>>(Abf, Brows);
    } else {
        float* agg = (float*)(ws + mark);
        hipMemsetAsync(agg, 0, (size_t)N * 4, stream);
        const int sblocks = (E + 255) / 256;
        scatter_kernel<<<sblocks, 256, 0, stream>>>(edges, inputs, gcn_w, agg, flag, E);
        act_kernel<<<(Brows * KPAD) / 256, 256, 0, stream>>>(agg, gcn_b, Abf);
    }

    transposeW1<<<dim3(H1DIM / 32, KPAD / 32), dim3(32, 8), 0, stream>>>(W1, W1T);
    transposeW2<<<dim3(4, H1DIM / 32), dim3(32, 8), 0, stream>>>(W2, W2Tp);

    gemm1_kernel<<<dim3(H1DIM / 128, Brows / 128), 256, 0, stream>>>(Abf, W1T, b1, H1);
    gemm2_kernel<<<dim3(KSPLIT, Brows / 64), 256, 0, stream>>>(H1, W2Tp, b2, out);
}